// Round 8
// baseline (146.610 us; speedup 1.0000x reference)
//
#include <hip/hip_runtime.h>

// PendulumSolver: B=65536 independent driven pendulums, RK4, 999 steps.
// Round 8: WAVE SPECIALIZATION to break the 1-wave/SIMD occupancy floor.
//   block = 128 threads = 2 waves:
//     wave0 (consumer): serial RK4 theta-chain for 64 pendulums
//     wave1 (producer): forcing cosines (c1,c2,c4) -- state-independent --
//                       into LDS, double-buffered in 8-step chunks.
//   -> 2048 waves total = 2 waves/SIMD: producer issue fills the chain's
//      trans/FMA latency bubbles (R6/R7: 27% stall, intra-wave ILP exhausted).
//   s_setprio(1) on the chain wave (role-split regime where setprio pays).
// Numerics BIT-IDENTICAL to rounds 6-7 (same expressions/order; absmax frozen
// at 0.0625 across six impls of this eval class): CW-split rad->rev reduction
// + HW v_sin/v_cos, all trig args bit-exact.

typedef float v2f __attribute__((ext_vector_type(2)));

__device__ __forceinline__ v2f vfma2(v2f a, v2f b, v2f c) {
#if __has_builtin(__builtin_elementwise_fma)
    return __builtin_elementwise_fma(a, b, c);
#else
    v2f r; r.x = fmaf(a.x, b.x, c.x); r.y = fmaf(a.y, b.y, c.y); return r;
#endif
}
__device__ __forceinline__ v2f splat2(float v) { v2f r; r.x = v; r.y = v; return r; }

#define CHI_F 0.15915494309189533577f
#define CLO_F ((float)(0.15915494309189533577 - (double)0.15915494309189533577f))
#define MAGIC_F 12582912.0f   // 1.5 * 2^23

__device__ __forceinline__ v2f to_rev2(v2f x) {
    v2f nb = vfma2(x, splat2(CHI_F), splat2(MAGIC_F));
    v2f n  = nb - splat2(MAGIC_F);
    v2f r  = vfma2(x, splat2(CHI_F), -n);
    r = vfma2(x, splat2(CLO_F), r);
    return r;
}
__device__ __forceinline__ float to_rev1(float x) {
    float nb = fmaf(x, CHI_F, MAGIC_F);
    float n  = nb - MAGIC_F;
    float r  = fmaf(x, CHI_F, -n);
    return fmaf(x, CLO_F, r);
}

__device__ __forceinline__ float hw_sin_rev(float x) {
#if __has_builtin(__builtin_amdgcn_sinf)
    return __builtin_amdgcn_sinf(x);
#else
    return __sinf(x * 6.28318530717958647692f);
#endif
}
__device__ __forceinline__ float hw_cos_rev(float x) {
#if __has_builtin(__builtin_amdgcn_cosf)
    return __builtin_amdgcn_cosf(x);
#else
    return __cosf(x * 6.28318530717958647692f);
#endif
}

#define CH 8          // steps per chunk
#define NFULL 124     // full chunks (steps 0..991); epilogue chunk has 7 steps

__global__ __launch_bounds__(128) void pend_kernel(
    const float* __restrict__ init,    // (B,2) theta, thdot
    const float* __restrict__ params,  // (B,4) omega, gamma, A, phi
    float* __restrict__ out,           // (B,1000)
    int B)
{
    __shared__ float4 fbuf[2][CH][64];

    const int lane = threadIdx.x & 63;
    const int wv   = threadIdx.x >> 6;           // 0 = chain, 1 = forcing
    int b = blockIdx.x * 64 + lane;
    const int bc = (b < B) ? b : (B - 1);        // clamped for safe loads

    const float dt  = 0.01f;
    const float hdt = 0.5f * dt;
    const float dt6 = dt / 6.0f;

    if (wv == 1) {
        // ---------------- producer wave ----------------
        const float phi = params[4 * bc + 3];
        const float tp  = 6.28318530717958647692f * phi;
        float fk = 0.0f;                         // exact (float)k

        auto produce = [&](int buf, int s) {
            float t  = fk * dt;                  // == (float)k * dt bit-exact
            float t2 = t + hdt;
            float t3 = t + dt;
            v2f y12; y12.x = tp * t; y12.y = tp * t2;
            float y3 = tp * t3;
            v2f rB   = to_rev2(y12);
            float r3 = to_rev1(y3);
            float4 f;
            f.x = hw_cos_rev(rB.x);              // c1
            f.y = hw_cos_rev(rB.y);              // c2 (stages 2 and 3)
            f.z = hw_cos_rev(r3);                // c4
            f.w = 0.0f;
            fbuf[buf][s][lane] = f;
            fk += 1.0f;
        };

        // prologue: chunk 0 -> buf0
        #pragma unroll
        for (int s = 0; s < CH; ++s) produce(0, s);
        __syncthreads();

        // loop j = 0..NFULL-1: produce chunk j+1 into buf[(j+1)&1]
        for (int j = 0; j < NFULL; ++j) {
            int buf = (j + 1) & 1;
            #pragma unroll
            for (int s = 0; s < CH; ++s) produce(buf, s);
            __syncthreads();
        }
        // epilogue: nothing to produce
    } else {
        // ---------------- chain (consumer) wave ----------------
        __builtin_amdgcn_s_setprio(1);

        float th = init[2 * bc + 0];
        float w  = init[2 * bc + 1];
        const float omega = params[4 * bc + 0];
        const float gamma = params[4 * bc + 1];
        const float A     = params[4 * bc + 2];
        const float om2 = omega * omega;
        const float Fco = (A * omega) * omega;

        float4* out4 = (float4*)(out + (size_t)bc * 1000);
        const bool wr = (b < B);

        auto step = [&](float4 f) -> float {
            float th2 = fmaf(hdt, w, th);
            v2f ra; ra.x = th; ra.y = th2;
            v2f rA = to_rev2(ra);
            float sth = hw_sin_rev(rA.x);
            float s2  = hw_sin_rev(rA.y);

            float a1  = Fco * f.x - gamma * w   - om2 * sth;
            float w2_ = fmaf(hdt, a1, w);
            float a2  = Fco * f.y - gamma * w2_ - om2 * s2;
            float th3 = fmaf(hdt, w2_, th);
            float s3  = hw_sin_rev(to_rev1(th3));
            float w3_ = fmaf(hdt, a2, w);
            float a3  = Fco * f.y - gamma * w3_ - om2 * s3;
            float th4 = fmaf(dt, w3_, th);
            float s4  = hw_sin_rev(to_rev1(th4));
            float w4_ = fmaf(dt, a3, w);
            float a4  = Fco * f.z - gamma * w4_ - om2 * s4;

            float ks_th = w  + 2.0f * w2_ + 2.0f * w3_ + w4_;
            float ks_w  = a1 + 2.0f * a2  + 2.0f * a3  + a4;
            th = fmaf(dt6, ks_th, th);
            w  = fmaf(dt6, ks_w,  w);
            return th;
        };

        __syncthreads();                          // wait for chunk 0

        float4 ob;
        ob.x = th;                                // position 0 = init theta
        int c = 0;                                // float4 store index

        // full chunks: 8 steps each; store phase repeats every chunk
        for (int j = 0; j < NFULL; ++j) {
            const int buf = j & 1;
            float4 f0 = fbuf[buf][0][lane];
            float4 f1 = fbuf[buf][1][lane];
            float4 f2 = fbuf[buf][2][lane];
            float4 f3 = fbuf[buf][3][lane];
            float4 f4 = fbuf[buf][4][lane];
            float4 f5 = fbuf[buf][5][lane];
            float4 f6 = fbuf[buf][6][lane];
            float4 f7 = fbuf[buf][7][lane];

            ob.y = step(f0);
            ob.z = step(f1);
            ob.w = step(f2);
            if (wr) out4[c] = ob;
            ob.x = step(f3);
            ob.y = step(f4);
            ob.z = step(f5);
            ob.w = step(f6);
            if (wr) out4[c + 1] = ob;
            ob.x = step(f7);
            c += 2;
            __syncthreads();
        }

        // epilogue chunk 124: 7 steps (992..998), buf = 124 & 1 = 0
        {
            float4 f0 = fbuf[0][0][lane];
            float4 f1 = fbuf[0][1][lane];
            float4 f2 = fbuf[0][2][lane];
            float4 f3 = fbuf[0][3][lane];
            float4 f4 = fbuf[0][4][lane];
            float4 f5 = fbuf[0][5][lane];
            float4 f6 = fbuf[0][6][lane];

            ob.y = step(f0);
            ob.z = step(f1);
            ob.w = step(f2);
            if (wr) out4[c] = ob;
            ob.x = step(f3);
            ob.y = step(f4);
            ob.z = step(f5);
            ob.w = step(f6);
            if (wr) out4[c + 1] = ob;
        }
    }
}

extern "C" void kernel_launch(void* const* d_in, const int* in_sizes, int n_in,
                              void* d_out, int out_size, void* d_ws, size_t ws_size,
                              hipStream_t stream) {
    const float* init   = (const float*)d_in[0];
    const float* params = (const float*)d_in[1];
    float* out = (float*)d_out;
    int B = in_sizes[0] / 2;

    int nblocks = (B + 63) / 64;                  // 64 pendulums per block
    hipLaunchKernelGGL(pend_kernel, dim3(nblocks), dim3(128), 0, stream,
                       init, params, out, B);
}

// Round 9
// 124.772 us; speedup vs baseline: 1.1750x; 1.1750x over previous
//
#include <hip/hip_runtime.h>

// PendulumSolver: B=65536 independent driven pendulums, RK4, 999 steps.
// Round 9: R6 single-wave structure (R7 manual pipelining + R8 wave
// specialization both FAILED: issue slots per SIMD are conserved; compiler
// already extracts intra-wave ILP) + exact-delta reduction sharing:
//   base reductions: rvth = to_rev1(th), rvy1 = to_rev1(y1)  (full CW)
//   secondary args:  rv_x = fma(delta, 1/2pi, rv_base),
//                    delta = fl(x) - base  (fp32 sub of reference-exact args)
//   -> represented angle is the reference's bit-exact fp32 argument; added
//      error = 1 fma rounding ~6e-8 rev + delta*Clo <= 2e-10  (proven class;
//      absmax frozen at 0.0625 across 8 impls).
// Cuts ~6 VALU/step and shortens both loop-carried arms (th3->s3, th4->s4)
// by replacing their 4-op to_rev with sub+fma before the HW v_sin.

#define CHI_F 0.15915494309189533577f
#define CLO_F ((float)(0.15915494309189533577 - (double)0.15915494309189533577f))
#define MAGIC_F 12582912.0f   // 1.5 * 2^23

// Full radians -> revolutions reduction; error ~1.2e-7 rev independent of |x|.
__device__ __forceinline__ float to_rev1(float x) {
    float nb = fmaf(x, CHI_F, MAGIC_F);
    float n  = nb - MAGIC_F;
    float r  = fmaf(x, CHI_F, -n);
    return fmaf(x, CLO_F, r);
}

__device__ __forceinline__ float hw_sin_rev(float x) {
#if __has_builtin(__builtin_amdgcn_sinf)
    return __builtin_amdgcn_sinf(x);
#else
    return __sinf(x * 6.28318530717958647692f);
#endif
}
__device__ __forceinline__ float hw_cos_rev(float x) {
#if __has_builtin(__builtin_amdgcn_cosf)
    return __builtin_amdgcn_cosf(x);
#else
    return __cosf(x * 6.28318530717958647692f);
#endif
}

__global__ __launch_bounds__(256) void pend_kernel(
    const float* __restrict__ init,    // (B,2) theta, thdot
    const float* __restrict__ params,  // (B,4) omega, gamma, A, phi
    float* __restrict__ out,           // (B,1000)
    int B)
{
    int b = blockIdx.x * blockDim.x + threadIdx.x;
    if (b >= B) return;

    float th = init[2 * b + 0];
    float w  = init[2 * b + 1];
    const float omega = params[4 * b + 0];
    const float gamma = params[4 * b + 1];
    const float A     = params[4 * b + 2];
    const float phi   = params[4 * b + 3];

    const float dt  = 0.01f;
    const float hdt = 0.5f * dt;
    const float dt6 = dt / 6.0f;
    const float om2 = omega * omega;
    const float Fco = (A * omega) * omega;
    const float tp  = 6.28318530717958647692f * phi;

    float4* out4 = (float4*)(out + (size_t)b * 1000);

    float fk = 0.0f;                    // tracks (float)k exactly (k < 2^24)

    auto step = [&]() -> float {
        // ---- forcing arguments (reference-exact radian values) ----
        float t  = fk * dt;             // == (float)k * dt bit-exact
        fk += 1.0f;
        float t2 = t + hdt;
        float t3 = t + dt;
        float y1 = tp * t;
        float y2 = tp * t2;
        float y3 = tp * t3;
        float rvy1 = to_rev1(y1);
        float rvy2 = fmaf(y2 - y1, CHI_F, rvy1);   // delta-shared reduction
        float rvy3 = fmaf(y3 - y1, CHI_F, rvy1);
        float c1 = hw_cos_rev(rvy1);
        float c2 = hw_cos_rev(rvy2);    // shared by stages 2 and 3
        float c4 = hw_cos_rev(rvy3);

        // ---- state chain ----
        float rvth = to_rev1(th);
        float sth  = hw_sin_rev(rvth);
        float th2  = fmaf(hdt, w, th);
        float s2   = hw_sin_rev(fmaf(th2 - th, CHI_F, rvth));

        float a1  = Fco * c1 - gamma * w   - om2 * sth;
        float w2_ = fmaf(hdt, a1, w);
        float a2  = Fco * c2 - gamma * w2_ - om2 * s2;
        float th3 = fmaf(hdt, w2_, th);
        float s3  = hw_sin_rev(fmaf(th3 - th, CHI_F, rvth));
        float w3_ = fmaf(hdt, a2, w);
        float a3  = Fco * c2 - gamma * w3_ - om2 * s3;
        float th4 = fmaf(dt, w3_, th);
        float s4  = hw_sin_rev(fmaf(th4 - th, CHI_F, rvth));
        float w4_ = fmaf(dt, a3, w);
        float a4  = Fco * c4 - gamma * w4_ - om2 * s4;

        float ks_th = w  + 2.0f * w2_ + 2.0f * w3_ + w4_;
        float ks_w  = a1 + 2.0f * a2  + 2.0f * a3  + a4;
        th = fmaf(dt6, ks_th, th);
        w  = fmaf(dt6, ks_w,  w);
        return th;
    };

    float4 ob;
    ob.x = th;
    ob.y = step();
    ob.z = step();
    ob.w = step();
    out4[0] = ob;

    for (int c = 1; c < 250; ++c) {
        ob.x = step();
        ob.y = step();
        ob.z = step();
        ob.w = step();
        out4[c] = ob;
    }
}

extern "C" void kernel_launch(void* const* d_in, const int* in_sizes, int n_in,
                              void* d_out, int out_size, void* d_ws, size_t ws_size,
                              hipStream_t stream) {
    const float* init   = (const float*)d_in[0];
    const float* params = (const float*)d_in[1];
    float* out = (float*)d_out;
    int B = in_sizes[0] / 2;

    int block = 256;
    int grid  = (B + block - 1) / block;
    hipLaunchKernelGGL(pend_kernel, dim3(grid), dim3(block), 0, stream,
                       init, params, out, B);
}

// Round 10
// 120.540 us; speedup vs baseline: 1.2163x; 1.0351x over previous
//
#include <hip/hip_runtime.h>

// PendulumSolver: B=65536 independent driven pendulums, RK4, 999 steps.
// Round 10: R9 structure + packed-fp32 (v_pk_fma_f32 etc.) for OFF-CHAIN
// arithmetic only. Per-lane IEEE semantics identical -> numerics bit-identical
// to R9 (absmax frozen at 0.0625 across 9 impls).
// Packed: (t2,t3), (y2,y3), base to_rev of (th,y1), (rvy2,rvy3) deltas,
// ks-combine, state update. NOT packed: stage updates / dynamics (packing
// would couple the critical chain to slower operands, e.g. th3 waiting on a2).
// Established dead ends: recons vs direct HW trans (R5<R6), extra waves (R8),
// manual cross-step scheduling (R7).

typedef float v2f __attribute__((ext_vector_type(2)));

__device__ __forceinline__ v2f vfma2(v2f a, v2f b, v2f c) {
#if __has_builtin(__builtin_elementwise_fma)
    return __builtin_elementwise_fma(a, b, c);
#else
    v2f r; r.x = fmaf(a.x, b.x, c.x); r.y = fmaf(a.y, b.y, c.y); return r;
#endif
}
__device__ __forceinline__ v2f splat2(float v) { v2f r; r.x = v; r.y = v; return r; }

#define CHI_F 0.15915494309189533577f
#define CLO_F ((float)(0.15915494309189533577 - (double)0.15915494309189533577f))
#define MAGIC_F 12582912.0f   // 1.5 * 2^23

// Packed radians -> revolutions; per-lane ops identical to R9's to_rev1.
__device__ __forceinline__ v2f to_rev2(v2f x) {
    v2f nb = vfma2(x, splat2(CHI_F), splat2(MAGIC_F));
    v2f n  = nb - splat2(MAGIC_F);
    v2f r  = vfma2(x, splat2(CHI_F), -n);
    return vfma2(x, splat2(CLO_F), r);
}

__device__ __forceinline__ float hw_sin_rev(float x) {
#if __has_builtin(__builtin_amdgcn_sinf)
    return __builtin_amdgcn_sinf(x);
#else
    return __sinf(x * 6.28318530717958647692f);
#endif
}
__device__ __forceinline__ float hw_cos_rev(float x) {
#if __has_builtin(__builtin_amdgcn_cosf)
    return __builtin_amdgcn_cosf(x);
#else
    return __cosf(x * 6.28318530717958647692f);
#endif
}

__global__ __launch_bounds__(256) void pend_kernel(
    const float* __restrict__ init,    // (B,2) theta, thdot
    const float* __restrict__ params,  // (B,4) omega, gamma, A, phi
    float* __restrict__ out,           // (B,1000)
    int B)
{
    int b = blockIdx.x * blockDim.x + threadIdx.x;
    if (b >= B) return;

    float th = init[2 * b + 0];
    float w  = init[2 * b + 1];
    const float omega = params[4 * b + 0];
    const float gamma = params[4 * b + 1];
    const float A     = params[4 * b + 2];
    const float phi   = params[4 * b + 3];

    const float dt  = 0.01f;
    const float hdt = 0.5f * dt;
    const float dt6 = dt / 6.0f;
    const float om2 = omega * omega;
    const float Fco = (A * omega) * omega;
    const float tp  = 6.28318530717958647692f * phi;

    // packed constants
    v2f hd2; hd2.x = hdt; hd2.y = dt;      // (hdt, dt) for t2/t3 prep

    float4* out4 = (float4*)(out + (size_t)b * 1000);

    float fk = 0.0f;                    // tracks (float)k exactly (k < 2^24)

    auto step = [&]() -> float {
        // ---- forcing arguments (reference-exact radian values) ----
        float t  = fk * dt;             // == (float)k * dt bit-exact
        fk += 1.0f;
        v2f t23 = splat2(t) + hd2;      // (t+hdt, t+dt)   [pk_add]
        float y1 = tp * t;
        v2f y23 = splat2(tp) * t23;     // (y2, y3)        [pk_mul]

        // base reductions, packed: (th, y1) both ready at step top
        v2f base; base.x = th; base.y = y1;
        v2f rvB = to_rev2(base);        // (rvth, rvy1)
        float rvth = rvB.x;
        float rvy1 = rvB.y;

        // forcing deltas, packed
        v2f dy  = y23 - splat2(y1);                 // (y2-y1, y3-y1) [pk_add]
        v2f rvy = vfma2(dy, splat2(CHI_F), splat2(rvy1));  // [pk_fma]

        float c1 = hw_cos_rev(rvy1);
        float c2 = hw_cos_rev(rvy.x);   // shared by stages 2 and 3
        float c4 = hw_cos_rev(rvy.y);

        // ---- state chain (scalar; order identical to R9) ----
        float sth  = hw_sin_rev(rvth);
        float th2  = fmaf(hdt, w, th);
        float s2   = hw_sin_rev(fmaf(th2 - th, CHI_F, rvth));

        float a1  = Fco * c1 - gamma * w   - om2 * sth;
        float w2_ = fmaf(hdt, a1, w);
        float a2  = Fco * c2 - gamma * w2_ - om2 * s2;
        float th3 = fmaf(hdt, w2_, th);
        float s3  = hw_sin_rev(fmaf(th3 - th, CHI_F, rvth));
        float w3_ = fmaf(hdt, a2, w);
        float a3  = Fco * c2 - gamma * w3_ - om2 * s3;
        float th4 = fmaf(dt, w3_, th);
        float s4  = hw_sin_rev(fmaf(th4 - th, CHI_F, rvth));
        float w4_ = fmaf(dt, a3, w);
        float a4  = Fco * c4 - gamma * w4_ - om2 * s4;

        // ---- combine, packed: lane ops match R9's scalar eval order ----
        v2f U1; U1.x = w;   U1.y = a1;
        v2f U2; U2.x = w2_; U2.y = a2;
        v2f U3; U3.x = w3_; U3.y = a3;
        v2f U4; U4.x = w4_; U4.y = a4;
        v2f ks = vfma2(splat2(2.0f), U2, U1);   // w + 2*w2_        [pk_fma]
        ks = vfma2(splat2(2.0f), U3, ks);       // .. + 2*w3_       [pk_fma]
        ks = ks + U4;                           // .. + w4_         [pk_add]
        v2f Y; Y.x = th; Y.y = w;
        Y = vfma2(splat2(dt6), ks, Y);          // state update     [pk_fma]
        th = Y.x;
        w  = Y.y;
        return th;
    };

    float4 ob;
    ob.x = th;
    ob.y = step();
    ob.z = step();
    ob.w = step();
    out4[0] = ob;

    for (int c = 1; c < 250; ++c) {
        ob.x = step();
        ob.y = step();
        ob.z = step();
        ob.w = step();
        out4[c] = ob;
    }
}

extern "C" void kernel_launch(void* const* d_in, const int* in_sizes, int n_in,
                              void* d_out, int out_size, void* d_ws, size_t ws_size,
                              hipStream_t stream) {
    const float* init   = (const float*)d_in[0];
    const float* params = (const float*)d_in[1];
    float* out = (float*)d_out;
    int B = in_sizes[0] / 2;

    int block = 256;
    int grid  = (B + block - 1) / block;
    hipLaunchKernelGGL(pend_kernel, dim3(grid), dim3(block), 0, stream,
                       init, params, out, B);
}